// Round 4
// baseline (288.282 us; speedup 1.0000x reference)
//
#include <hip/hip_runtime.h>
#include <hip/hip_bf16.h>

typedef __bf16 bf16;
typedef __bf16 bf16x8 __attribute__((ext_vector_type(8)));
typedef float f32x4 __attribute__((ext_vector_type(4)));

static __device__ __forceinline__ f32x4 mfma16(bf16x8 a, bf16x8 b, f32x4 c) {
  return __builtin_amdgcn_mfma_f32_16x16x32_bf16(a, b, c, 0, 0, 0);
}

static __device__ __forceinline__ bf16x8 cvt8(const float* p) {
  f32x4 a0 = *(const f32x4*)p;
  f32x4 a1 = *(const f32x4*)(p + 4);
  bf16x8 r;
#pragma unroll
  for (int j = 0; j < 4; ++j) { r[j] = (bf16)a0[j]; r[4 + j] = (bf16)a1[j]; }
  return r;
}

// ---------------------------------------------------------------------------
// prep_wt: Wt[c][k] = W*(k, c), f32 -> bf16.  c: 0..31 Wq | 32..63 Wk | 64..319 Wv
// ---------------------------------------------------------------------------
__global__ void prep_wt(const float* __restrict__ Wq, const float* __restrict__ Wk,
                        const float* __restrict__ Wv, bf16* __restrict__ Wt) {
  int c = blockIdx.x;   // 0..319
  int k = threadIdx.x;  // 0..255
  float v;
  if (c < 32)       v = Wq[k * 32 + c];
  else if (c < 64)  v = Wk[k * 32 + (c - 32)];
  else              v = Wv[k * 256 + (c - 64)];
  Wt[c * 256 + k] = (bf16)v;
}

// ---------------------------------------------------------------------------
// qkv_gemm: rows = gridDim.x*64, cols = 320 (q|k|v).  x f32 -> bf16 frags.
// Writes Q[nb][4096][32], K same, Vt[nb][256][4096] (bf16).
// ---------------------------------------------------------------------------
__global__ __launch_bounds__(256) void qkv_gemm(
    const float* __restrict__ x, const bf16* __restrict__ Wt,
    const float* __restrict__ bq, const float* __restrict__ bk,
    const float* __restrict__ bv,
    bf16* __restrict__ Qd, bf16* __restrict__ Kd, bf16* __restrict__ Vt) {
  int tid = threadIdx.x;
  int lane = tid & 63, w = tid >> 6;
  int lw = lane & 15, qq = lane >> 4;
  int r0 = blockIdx.x * 64, c0 = blockIdx.y * 64;

  const float* arow = x + (size_t)(r0 + 16 * w + lw) * 256;
  f32x4 acc[4] = {};
#pragma unroll
  for (int kc = 0; kc < 8; ++kc) {
    bf16x8 a = cvt8(arow + kc * 32 + qq * 8);
#pragma unroll
    for (int t = 0; t < 4; ++t) {
      bf16x8 b = *(const bf16x8*)(Wt + (size_t)(c0 + 16 * t + lw) * 256 + kc * 32 + qq * 8);
      acc[t] = mfma16(a, b, acc[t]);
    }
  }
  // C/D: col = lane&15, row = (lane>>4)*4 + i  [m89]
#pragma unroll
  for (int t = 0; t < 4; ++t) {
    int c = c0 + 16 * t + lw;
    float bias = (c < 32) ? bq[c] : (c < 64) ? bk[c - 32] : bv[c - 64];
#pragma unroll
    for (int i = 0; i < 4; ++i) {
      int R = r0 + 16 * w + 4 * qq + i;
      int bb = R >> 12, n = R & 4095;
      bf16 hv = (bf16)(acc[t][i] + bias);
      if (c < 32)       Qd[((size_t)(bb << 12) + n) * 32 + c] = hv;
      else if (c < 64)  Kd[((size_t)(bb << 12) + n) * 32 + (c - 32)] = hv;
      else              Vt[((size_t)bb * 256 + (c - 64)) * 4096 + n] = hv;
    }
  }
}

// ---------------------------------------------------------------------------
// flash_attn: one block per (64-row q-tile, local batch). 4 waves.
// Output is FLOAT32 (the reference's output dtype).
// ---------------------------------------------------------------------------
__global__ __launch_bounds__(256) void flash_attn(
    const bf16* __restrict__ Qd, const bf16* __restrict__ Kd,
    const bf16* __restrict__ Vt, const float* __restrict__ x,
    const float* __restrict__ gamma, float* __restrict__ out) {
  __shared__ __align__(16) bf16 Pl[64 * 72];   // P tile, padded stride 72
  __shared__ __align__(16) float alpha_s[64];
  __shared__ __align__(16) float lsum_s[64];

  int tid = threadIdx.x;
  int lane = tid & 63, w = tid >> 6;
  int lw = lane & 15, qq = lane >> 4;
  int bb = blockIdx.y;
  int r0 = blockIdx.x * 64;

  const bf16* Qb = Qd + ((size_t)bb << 12) * 32;
  const bf16* Kb = Kd + ((size_t)bb << 12) * 32;
  const bf16* Vb = Vt + (size_t)bb * 256 * 4096;

  bf16x8 qf = *(const bf16x8*)(Qb + (size_t)(r0 + 16 * w + lw) * 32 + qq * 8);

  float m_i[4], l_i[4];
#pragma unroll
  for (int i = 0; i < 4; ++i) { m_i[i] = -INFINITY; l_i[i] = 0.f; }
  f32x4 o[4][4] = {};  // [m-tile][c-tile]: rows 16m+4qq+i, ch 64w+16t+lw

  for (int j = 0; j < 64; ++j) {
    int n0 = j * 64;
    f32x4 s[4];
#pragma unroll
    for (int t = 0; t < 4; ++t) {
      bf16x8 kf = *(const bf16x8*)(Kb + (size_t)(n0 + 16 * t + lw) * 32 + qq * 8);
      f32x4 z = {};
      s[t] = mfma16(qf, kf, z);
    }
#pragma unroll
    for (int i = 0; i < 4; ++i) {
      float mx = fmaxf(fmaxf(s[0][i], s[1][i]), fmaxf(s[2][i], s[3][i]));
      mx = fmaxf(mx, __shfl_xor(mx, 1));
      mx = fmaxf(mx, __shfl_xor(mx, 2));
      mx = fmaxf(mx, __shfl_xor(mx, 4));
      mx = fmaxf(mx, __shfl_xor(mx, 8));
      float mnew = fmaxf(m_i[i], mx);
      float al = __expf(m_i[i] - mnew);   // first tile: exp(-inf) = 0
      float sum = 0.f;
      int prow = 16 * w + 4 * qq + i;
#pragma unroll
      for (int t = 0; t < 4; ++t) {
        float p = __expf(s[t][i] - mnew);
        sum += p;
        Pl[prow * 72 + 16 * t + lw] = (bf16)p;
      }
      sum += __shfl_xor(sum, 1);
      sum += __shfl_xor(sum, 2);
      sum += __shfl_xor(sum, 4);
      sum += __shfl_xor(sum, 8);
      l_i[i] = l_i[i] * al + sum;
      m_i[i] = mnew;
      if (lw == 0) alpha_s[prow] = al;
    }
    __syncthreads();
#pragma unroll
    for (int m = 0; m < 4; ++m) {
      f32x4 al4 = *(const f32x4*)&alpha_s[16 * m + 4 * qq];
#pragma unroll
      for (int t = 0; t < 4; ++t) o[m][t] *= al4;
    }
#pragma unroll
    for (int kc = 0; kc < 2; ++kc) {
      bf16x8 af[4];
#pragma unroll
      for (int m = 0; m < 4; ++m)
        af[m] = *(const bf16x8*)&Pl[(16 * m + lw) * 72 + kc * 32 + qq * 8];
#pragma unroll
      for (int t = 0; t < 4; ++t) {
        bf16x8 vf = *(const bf16x8*)(Vb + (size_t)(64 * w + 16 * t + lw) * 4096 + n0 + kc * 32 + qq * 8);
#pragma unroll
        for (int m = 0; m < 4; ++m) o[m][t] = mfma16(af[m], vf, o[m][t]);
      }
    }
    __syncthreads();
  }

#pragma unroll
  for (int i = 0; i < 4; ++i)
    if (lw == 0) lsum_s[16 * w + 4 * qq + i] = l_i[i];
  __syncthreads();
  float g = gamma[0];
#pragma unroll
  for (int m = 0; m < 4; ++m) {
    f32x4 lv = *(const f32x4*)&lsum_s[16 * m + 4 * qq];
#pragma unroll
    for (int i = 0; i < 4; ++i) {
      float rinv = 1.f / lv[i];
      int row = r0 + 16 * m + 4 * qq + i;
      size_t base = (((size_t)bb << 12) + row) * 256 + 64 * w;
#pragma unroll
      for (int t = 0; t < 4; ++t) {
        int c = 16 * t + lw;
        out[base + c] = g * (o[m][t][i] * rinv) + x[base + c];  // f32 store
      }
    }
  }
}

extern "C" void kernel_launch(void* const* d_in, const int* in_sizes, int n_in,
                              void* d_out, int out_size, void* d_ws, size_t ws_size,
                              hipStream_t stream) {
  const float* x     = (const float*)d_in[0];
  const float* Wq    = (const float*)d_in[1];
  const float* bq    = (const float*)d_in[2];
  const float* Wk    = (const float*)d_in[3];
  const float* bk    = (const float*)d_in[4];
  const float* Wv    = (const float*)d_in[5];
  const float* bv    = (const float*)d_in[6];
  const float* gamma = (const float*)d_in[7];
  float* out = (float*)d_out;

  const size_t WT_E = 320 * 256;
  const size_t QK_E = (size_t)4096 * 32;   // per-batch Q (or K)
  const size_t VT_E = (size_t)256 * 4096;  // per-batch Vt

  size_t full_bytes = (WT_E + 4 * 2 * QK_E + 4 * VT_E) * sizeof(bf16);  // ~10.2 MB

  bf16* Wt = (bf16*)d_ws;
  prep_wt<<<dim3(320), dim3(256), 0, stream>>>(Wq, Wk, Wv, Wt);

  if (ws_size >= full_bytes) {
    bf16* Qd = Wt + WT_E;
    bf16* Kd = Qd + 4 * QK_E;
    bf16* Vt = Kd + 4 * QK_E;
    qkv_gemm<<<dim3(256, 5), dim3(256), 0, stream>>>(x, Wt, bq, bk, bv, Qd, Kd, Vt);
    flash_attn<<<dim3(64, 4), dim3(256), 0, stream>>>(Qd, Kd, Vt, x, gamma, out);
  } else {
    bf16* Qd = Wt + WT_E;
    bf16* Kd = Qd + QK_E;
    bf16* Vt = Kd + QK_E;
    for (int b = 0; b < 4; ++b) {
      const float* xb = x + (size_t)b * 4096 * 256;
      float* outb = out + (size_t)b * 4096 * 256;
      qkv_gemm<<<dim3(64, 5), dim3(256), 0, stream>>>(xb, Wt, bq, bk, bv, Qd, Kd, Vt);
      flash_attn<<<dim3(64, 1), dim3(256), 0, stream>>>(Qd, Kd, Vt, xb, gamma, outb);
    }
  }
}

// Round 5
// 254.442 us; speedup vs baseline: 1.1330x; 1.1330x over previous
//
#include <hip/hip_runtime.h>
#include <hip/hip_bf16.h>

typedef __bf16 bf16;
typedef __bf16 bf16x8 __attribute__((ext_vector_type(8)));
typedef float f32x4 __attribute__((ext_vector_type(4)));

static __device__ __forceinline__ f32x4 mfma16(bf16x8 a, bf16x8 b, f32x4 c) {
  return __builtin_amdgcn_mfma_f32_16x16x32_bf16(a, b, c, 0, 0, 0);
}

static __device__ __forceinline__ bf16x8 cvt8(const float* p) {
  f32x4 a0 = *(const f32x4*)p;
  f32x4 a1 = *(const f32x4*)(p + 4);
  bf16x8 r;
#pragma unroll
  for (int j = 0; j < 4; ++j) { r[j] = (bf16)a0[j]; r[4 + j] = (bf16)a1[j]; }
  return r;
}

// ---------------------------------------------------------------------------
// prep_wt: Wt[c][k] = W*(k, c), f32 -> bf16.  c: 0..31 Wq | 32..63 Wk | 64..319 Wv
// ---------------------------------------------------------------------------
__global__ void prep_wt(const float* __restrict__ Wq, const float* __restrict__ Wk,
                        const float* __restrict__ Wv, bf16* __restrict__ Wt) {
  int c = blockIdx.x;
  int k = threadIdx.x;
  float v;
  if (c < 32)       v = Wq[k * 32 + c];
  else if (c < 64)  v = Wk[k * 32 + (c - 32)];
  else              v = Wv[k * 256 + (c - 64)];
  Wt[c * 256 + k] = (bf16)v;
}

// ---------------------------------------------------------------------------
// qkv_gemm. Vt stores go through an LDS transpose so global writes are
// 128B-contiguous along n (the old path wrote 2B at 8KB stride).
// ---------------------------------------------------------------------------
__global__ __launch_bounds__(256) void qkv_gemm(
    const float* __restrict__ x, const bf16* __restrict__ Wt,
    const float* __restrict__ bq, const float* __restrict__ bk,
    const float* __restrict__ bv,
    bf16* __restrict__ Qd, bf16* __restrict__ Kd, bf16* __restrict__ Vt) {
  __shared__ __align__(16) bf16 tile[64 * 72];
  int tid = threadIdx.x;
  int lane = tid & 63, w = tid >> 6;
  int lw = lane & 15, qq = lane >> 4;
  int r0 = blockIdx.x * 64, c0 = blockIdx.y * 64;

  const float* arow = x + (size_t)(r0 + 16 * w + lw) * 256;
  f32x4 acc[4] = {};
#pragma unroll
  for (int kc = 0; kc < 8; ++kc) {
    bf16x8 a = cvt8(arow + kc * 32 + qq * 8);
#pragma unroll
    for (int t = 0; t < 4; ++t) {
      bf16x8 b = *(const bf16x8*)(Wt + (size_t)(c0 + 16 * t + lw) * 256 + kc * 32 + qq * 8);
      acc[t] = mfma16(a, b, acc[t]);
    }
  }
  // C/D: col = lane&15, row = (lane>>4)*4 + i  [m89]
  int bb = r0 >> 12, n0 = r0 & 4095;  // 64 rows never straddle a batch
  if (c0 == 0) {
    // Q (t=0,1) and K (t=2,3): direct stores, 32B runs per quad
#pragma unroll
    for (int t = 0; t < 4; ++t) {
      int c = 16 * t + lw;
      float bias = (c < 32) ? bq[c] : bk[c - 32];
#pragma unroll
      for (int i = 0; i < 4; ++i) {
        int n = n0 + 16 * w + 4 * qq + i;
        bf16 hv = (bf16)(acc[t][i] + bias);
        if (c < 32) Qd[((size_t)(bb << 12) + n) * 32 + c] = hv;
        else        Kd[((size_t)(bb << 12) + n) * 32 + (c - 32)] = hv;
      }
    }
  } else {
    // V: stage [col][row] in LDS, then write Vt rows contiguously along n
#pragma unroll
    for (int t = 0; t < 4; ++t) {
      int cl = 16 * t + lw;
      float bias = bv[c0 - 64 + cl];
#pragma unroll
      for (int i = 0; i < 4; ++i)
        tile[cl * 72 + 16 * w + 4 * qq + i] = (bf16)(acc[t][i] + bias);
    }
    __syncthreads();
    int nl = tid & 63;   // n within tile
    int cs = tid >> 6;   // starting col
#pragma unroll
    for (int cc = 0; cc < 4; ++cc) {
      int cl = 4 * cc + cs;  // wait-free spread: 4 iterations x 4 waves
      Vt[((size_t)bb * 256 + (c0 - 64) + cl) * 4096 + n0 + nl] = tile[cl * 72 + nl];
    }
#pragma unroll
    for (int cc = 16; cc < 64; cc += 16) {
      int cl = cc + cs * 4;
#pragma unroll
      for (int u = 0; u < 4; ++u)
        Vt[((size_t)bb * 256 + (c0 - 64) + cl + u) * 4096 + n0 + nl] =
            tile[(cl + u) * 72 + nl];
    }
  }
}

// ---------------------------------------------------------------------------
// flash_attn: 32-row q-tiles -> grid (128, nb) = 2 blocks/CU. 4 waves.
// Wave w: S+softmax for rows 16*(w&1)..+15 (pairs 0/2 and 1/3 duplicate),
// PV for all 32 rows x channels [64w, 64w+64). K/V frags double-buffered
// in registers (prefetch issued before each barrier, consumed after).
// ---------------------------------------------------------------------------
__global__ __launch_bounds__(256, 2) void flash_attn(
    const bf16* __restrict__ Qd, const bf16* __restrict__ Kd,
    const bf16* __restrict__ Vt, const float* __restrict__ x,
    const float* __restrict__ gamma, float* __restrict__ out) {
  __shared__ __align__(16) bf16 Pl[32 * 72];
  __shared__ __align__(16) float alpha_s[32];
  __shared__ __align__(16) float lsum_s[32];

  int tid = threadIdx.x;
  int lane = tid & 63, w = tid >> 6;
  int lw = lane & 15, qq = lane >> 4;
  int sg = w & 1;
  int bb = blockIdx.y;
  int r0 = blockIdx.x * 32;

  const bf16* Qb = Qd + ((size_t)bb << 12) * 32;
  const bf16* Kb = Kd + ((size_t)bb << 12) * 32;
  const bf16* Vb = Vt + (size_t)bb * 256 * 4096;

  bf16x8 qf = *(const bf16x8*)(Qb + (size_t)(r0 + 16 * sg + lw) * 32 + qq * 8);

  float m_i[4], l_i[4];
#pragma unroll
  for (int i = 0; i < 4; ++i) { m_i[i] = -INFINITY; l_i[i] = 0.f; }
  f32x4 o[2][4] = {};  // rows 16m+4qq+i, ch 64w+16t+lw

  // Double-buffered K/V fragments
  bf16x8 kbuf[2][4], vbuf[2][8];
#pragma unroll
  for (int t = 0; t < 4; ++t)
    kbuf[0][t] = *(const bf16x8*)(Kb + (size_t)(16 * t + lw) * 32 + qq * 8);
#pragma unroll
  for (int kc = 0; kc < 2; ++kc)
#pragma unroll
    for (int t = 0; t < 4; ++t)
      vbuf[0][kc * 4 + t] = *(const bf16x8*)(Vb + (size_t)(64 * w + 16 * t + lw) * 4096 + kc * 32 + qq * 8);

#pragma unroll 2
  for (int j = 0; j < 64; ++j) {
    int cur = j & 1, nxt = cur ^ 1;
    int n1 = ((j + 1) & 63) * 64;  // wraps on last iter: harmless valid loads

    // ---- S for this wave's 16 rows ----
    f32x4 s[4];
#pragma unroll
    for (int t = 0; t < 4; ++t) {
      f32x4 z = {};
      s[t] = mfma16(qf, kbuf[cur][t], z);
    }
    // prefetch K for j+1 (completes during softmax + barrier)
#pragma unroll
    for (int t = 0; t < 4; ++t)
      kbuf[nxt][t] = *(const bf16x8*)(Kb + (size_t)(n1 + 16 * t + lw) * 32 + qq * 8);

    // ---- online softmax, rows 16sg + 4qq + i ----
#pragma unroll
    for (int i = 0; i < 4; ++i) {
      float mx = fmaxf(fmaxf(s[0][i], s[1][i]), fmaxf(s[2][i], s[3][i]));
      mx = fmaxf(mx, __shfl_xor(mx, 1));
      mx = fmaxf(mx, __shfl_xor(mx, 2));
      mx = fmaxf(mx, __shfl_xor(mx, 4));
      mx = fmaxf(mx, __shfl_xor(mx, 8));
      float mnew = fmaxf(m_i[i], mx);
      float al = __expf(m_i[i] - mnew);
      float sum = 0.f;
      int prow = 16 * sg + 4 * qq + i;
#pragma unroll
      for (int t = 0; t < 4; ++t) {
        float p = __expf(s[t][i] - mnew);
        sum += p;
        Pl[prow * 72 + 16 * t + lw] = (bf16)p;  // waves (0,2)/(1,3) write identical data
      }
      sum += __shfl_xor(sum, 1);
      sum += __shfl_xor(sum, 2);
      sum += __shfl_xor(sum, 4);
      sum += __shfl_xor(sum, 8);
      l_i[i] = l_i[i] * al + sum;
      m_i[i] = mnew;
      if (lw == 0) alpha_s[prow] = al;
    }
    __syncthreads();

    // ---- rescale O ----
#pragma unroll
    for (int m = 0; m < 2; ++m) {
      f32x4 al4 = *(const f32x4*)&alpha_s[16 * m + 4 * qq];
#pragma unroll
      for (int t = 0; t < 4; ++t) o[m][t] *= al4;
    }
    // prefetch V for j+1 (completes during PV + barrier)
#pragma unroll
    for (int kc = 0; kc < 2; ++kc)
#pragma unroll
      for (int t = 0; t < 4; ++t)
        vbuf[nxt][kc * 4 + t] = *(const bf16x8*)(Vb + (size_t)(64 * w + 16 * t + lw) * 4096 + n1 + kc * 32 + qq * 8);

    // ---- O += P . V ----
#pragma unroll
    for (int kc = 0; kc < 2; ++kc) {
      bf16x8 af[2];
#pragma unroll
      for (int m = 0; m < 2; ++m)
        af[m] = *(const bf16x8*)&Pl[(16 * m + lw) * 72 + kc * 32 + qq * 8];
#pragma unroll
      for (int t = 0; t < 4; ++t)
#pragma unroll
        for (int m = 0; m < 2; ++m)
          o[m][t] = mfma16(af[m], vbuf[cur][kc * 4 + t], o[m][t]);
    }
    __syncthreads();
  }

#pragma unroll
  for (int i = 0; i < 4; ++i)
    if (lw == 0 && w < 2) lsum_s[16 * sg + 4 * qq + i] = l_i[i];
  __syncthreads();
  float g = gamma[0];
#pragma unroll
  for (int m = 0; m < 2; ++m) {
    f32x4 lv = *(const f32x4*)&lsum_s[16 * m + 4 * qq];
#pragma unroll
    for (int i = 0; i < 4; ++i) {
      float rinv = 1.f / lv[i];
      int row = r0 + 16 * m + 4 * qq + i;
      size_t base = (((size_t)bb << 12) + row) * 256 + 64 * w;
#pragma unroll
      for (int t = 0; t < 4; ++t)
        out[base + 16 * t + lw] = g * (o[m][t][i] * rinv) + x[base + 16 * t + lw];
    }
  }
}

extern "C" void kernel_launch(void* const* d_in, const int* in_sizes, int n_in,
                              void* d_out, int out_size, void* d_ws, size_t ws_size,
                              hipStream_t stream) {
  const float* x     = (const float*)d_in[0];
  const float* Wq    = (const float*)d_in[1];
  const float* bq    = (const float*)d_in[2];
  const float* Wk    = (const float*)d_in[3];
  const float* bk    = (const float*)d_in[4];
  const float* Wv    = (const float*)d_in[5];
  const float* bv    = (const float*)d_in[6];
  const float* gamma = (const float*)d_in[7];
  float* out = (float*)d_out;

  const size_t WT_E = 320 * 256;
  const size_t QK_E = (size_t)4096 * 32;
  const size_t VT_E = (size_t)256 * 4096;
  size_t full_bytes = (WT_E + 4 * 2 * QK_E + 4 * VT_E) * sizeof(bf16);

  bf16* Wt = (bf16*)d_ws;
  prep_wt<<<dim3(320), dim3(256), 0, stream>>>(Wq, Wk, Wv, Wt);

  if (ws_size >= full_bytes) {
    bf16* Qd = Wt + WT_E;
    bf16* Kd = Qd + 4 * QK_E;
    bf16* Vt = Kd + 4 * QK_E;
    qkv_gemm<<<dim3(256, 5), dim3(256), 0, stream>>>(x, Wt, bq, bk, bv, Qd, Kd, Vt);
    flash_attn<<<dim3(128, 4), dim3(256), 0, stream>>>(Qd, Kd, Vt, x, gamma, out);
  } else {
    bf16* Qd = Wt + WT_E;
    bf16* Kd = Qd + QK_E;
    bf16* Vt = Kd + QK_E;
    for (int b = 0; b < 4; ++b) {
      const float* xb = x + (size_t)b * 4096 * 256;
      float* outb = out + (size_t)b * 4096 * 256;
      qkv_gemm<<<dim3(64, 5), dim3(256), 0, stream>>>(xb, Wt, bq, bk, bv, Qd, Kd, Vt);
      flash_attn<<<dim3(128, 1), dim3(256), 0, stream>>>(Qd, Kd, Vt, xb, gamma, outb);
    }
  }
}